// Round 1
// baseline (149.715 us; speedup 1.0000x reference)
//
#include <hip/hip_runtime.h>
#include <math.h>

#define NB 128        // batch
#define N 256         // FFT size / image dim
#define NBINS 181
#define THRESH 90
#define CG 32         // columns per block in col pass

__device__ __forceinline__ int bitrev8(int i) { return (int)(__brev((unsigned)i) >> 24); }

// ---------------- Row pass: gray conversion + 256-pt FFT per row ----------------
// grid: NB*64 blocks, 256 threads. Each wave (4/block) does one row.
__global__ __launch_bounds__(256) void row_fft_kernel(const float* __restrict__ x,
                                                      float2* __restrict__ F) {
    __shared__ float s_re[4][N];
    __shared__ float s_im[4][N];
    __shared__ float tw_re[N/2];
    __shared__ float tw_im[N/2];

    const int t = threadIdx.x;
    const int wave = t >> 6;
    const int lane = t & 63;
    const int b  = blockIdx.x >> 6;
    const int rg = blockIdx.x & 63;
    const int row = rg * 4 + wave;

    if (t < N/2) {
        float s, c;
        sincosf(-6.283185307179586f * (float)t / (float)N, &s, &c);
        tw_re[t] = c; tw_im[t] = s;
    }

    const float* xr = x + (size_t)b * 3 * (N*N) + (size_t)row * N;
    #pragma unroll
    for (int k = 0; k < 4; ++k) {
        int i = lane + 64*k;
        float r  = xr[i];
        float g  = xr[i + N*N];
        float bl = xr[i + 2*N*N];
        float gray = 0.2989f*r + 0.587f*g + 0.114f*bl;
        int ri = bitrev8(i);
        s_re[wave][ri] = gray;
        s_im[wave][ri] = 0.0f;
    }
    __syncthreads();

    for (int s = 1; s <= 8; ++s) {
        const int half = 1 << (s-1);
        const int tstr = N >> s;
        #pragma unroll
        for (int k = 0; k < 2; ++k) {
            int bf  = lane + 64*k;          // 0..127, all pairs disjoint per stage
            int grp = bf >> (s-1);
            int j   = bf & (half-1);
            int i1  = grp*(half<<1) + j;
            int i2  = i1 + half;
            float wr = tw_re[j*tstr], wi = tw_im[j*tstr];
            float br = s_re[wave][i2], bi = s_im[wave][i2];
            float tr = br*wr - bi*wi;
            float ti = br*wi + bi*wr;
            float ar = s_re[wave][i1], ai = s_im[wave][i1];
            s_re[wave][i1] = ar + tr; s_im[wave][i1] = ai + ti;
            s_re[wave][i2] = ar - tr; s_im[wave][i2] = ai - ti;
        }
        __syncthreads();
    }

    float2* Frow = F + (size_t)b * (N*N) + (size_t)row * N;
    #pragma unroll
    for (int k = 0; k < 4; ++k) {
        int i = lane + 64*k;
        Frow[i] = make_float2(s_re[wave][i], s_im[wave][i]);
    }
}

// ------------- Col pass: 256-pt FFT per column + log|F| + radial binning -------------
// grid: NB*8 blocks (8 groups of 32 columns), 256 threads.
__global__ __launch_bounds__(256) void col_fft_kernel(const float2* __restrict__ F,
                                                      float* __restrict__ sums) {
    __shared__ float s_re[N*CG];
    __shared__ float s_im[N*CG];
    __shared__ float tw_re[N/2];
    __shared__ float tw_im[N/2];
    __shared__ float bins[192];

    const int t = threadIdx.x;
    const int c = t & (CG-1);
    const int q = t >> 5;               // 0..7
    const int b  = blockIdx.x >> 3;
    const int cg = blockIdx.x & 7;

    if (t < N/2) {
        float s, co;
        sincosf(-6.283185307179586f * (float)t / (float)N, &s, &co);
        tw_re[t] = co; tw_im[t] = s;
    }
    if (t < 192) bins[t] = 0.0f;

    const float2* base = F + (size_t)b * (N*N) + cg*CG;
    #pragma unroll 4
    for (int i = 0; i < 32; ++i) {
        int r = i*8 + q;
        float2 v = base[(size_t)r * N + c];
        int rr = bitrev8(r);
        s_re[rr*CG + c] = v.x;
        s_im[rr*CG + c] = v.y;
    }
    __syncthreads();

    for (int s = 1; s <= 8; ++s) {
        const int half = 1 << (s-1);
        const int tstr = N >> s;
        #pragma unroll 4
        for (int k = 0; k < 16; ++k) {
            int bf  = q*16 + k;          // 0..127
            int grp = bf >> (s-1);
            int j   = bf & (half-1);
            int i1  = (grp*(half<<1) + j)*CG + c;
            int i2  = i1 + half*CG;
            float wr = tw_re[j*tstr], wi = tw_im[j*tstr];
            float br = s_re[i2], bi = s_im[i2];
            float tr = br*wr - bi*wi;
            float ti = br*wi + bi*wr;
            float ar = s_re[i1], ai = s_im[i1];
            s_re[i1] = ar + tr; s_im[i1] = ai + ti;
            s_re[i2] = ar - tr; s_im[i2] = ai - ti;
        }
        __syncthreads();
    }

    // log-magnitude + fftshift + radial binning
    const int xcol = cg*CG + c;
    const float dx = (float)((xcol + 128) & 255) - 127.5f;
    #pragma unroll 4
    for (int i = 0; i < 32; ++i) {
        int u = i*8 + q;
        float re = s_re[u*CG + c], im = s_im[u*CG + c];
        float mag = logf(sqrtf(re*re + im*im) + 1e-8f);
        float dy = (float)((u + 128) & 255) - 127.5f;
        int bin = (int)sqrtf(dx*dx + dy*dy);
        atomicAdd(&bins[bin], mag);
    }
    __syncthreads();
    if (t < NBINS) atomicAdd(&sums[b*NBINS + t], bins[t]);
}

// ------------- Profile: counts, mean, min/max-normalize, dot with w -------------
// grid: NB blocks, 256 threads.
__global__ __launch_bounds__(256) void profile_kernel(const float* __restrict__ sums,
                                                      const float* __restrict__ w,
                                                      const float* __restrict__ bias,
                                                      float* __restrict__ out) {
    __shared__ int   cnt[192];
    __shared__ float prof[192];
    __shared__ float wred[4][3];

    const int t = threadIdx.x;
    const int b = blockIdx.x;
    if (t < 192) cnt[t] = 0;
    __syncthreads();

    {
        float dy = (float)t - 127.5f;
        for (int xx = 0; xx < 256; ++xx) {
            float dxx = (float)xx - 127.5f;
            int bin = (int)sqrtf(dxx*dxx + dy*dy);
            atomicAdd(&cnt[bin], 1);
        }
    }
    __syncthreads();
    if (t < NBINS) prof[t] = sums[b*NBINS + t] / (float)cnt[t];
    __syncthreads();

    float v = (t < NBINS) ? prof[t] : prof[0];
    float mn = v, mx = v;
    #pragma unroll
    for (int m = 32; m >= 1; m >>= 1) {
        mn = fminf(mn, __shfl_xor(mn, m));
        mx = fmaxf(mx, __shfl_xor(mx, m));
    }
    if ((t & 63) == 0) { wred[t>>6][0] = mn; wred[t>>6][1] = mx; }
    __syncthreads();
    if (t == 0) {
        float a = wred[0][0], z = wred[0][1];
        for (int i = 1; i < 4; ++i) { a = fminf(a, wred[i][0]); z = fmaxf(z, wred[i][1]); }
        wred[0][0] = a; wred[0][1] = z;
    }
    __syncthreads();
    const float mnv = wred[0][0], mxv = wred[0][1];

    float part = 0.0f;
    if (t < THRESH) {
        float f = (prof[(NBINS - THRESH) + t] - mnv) / (mxv - mnv);
        if (f != f) f = 0.0f;      // NaN -> 0 (matches jnp.where(isnan))
        part = f * w[t];
    }
    #pragma unroll
    for (int m = 32; m >= 1; m >>= 1) part += __shfl_xor(part, m);
    if ((t & 63) == 0) wred[t>>6][2] = part;
    __syncthreads();
    if (t == 0) out[b] = wred[0][2] + wred[1][2] + wred[2][2] + wred[3][2] + bias[0];
}

extern "C" void kernel_launch(void* const* d_in, const int* in_sizes, int n_in,
                              void* d_out, int out_size, void* d_ws, size_t ws_size,
                              hipStream_t stream) {
    const float* x    = (const float*)d_in[0];  // (128,3,256,256)
    const float* w    = (const float*)d_in[1];  // (1,90)
    const float* bias = (const float*)d_in[2];  // (1,)
    float* out = (float*)d_out;                 // (128,1)

    float2* F   = (float2*)d_ws;                                  // 128*256*256 complex = 64 MiB
    float* sums = (float*)((char*)d_ws + (size_t)NB * N * N * sizeof(float2));

    hipMemsetAsync(sums, 0, (size_t)NB * NBINS * sizeof(float), stream);
    row_fft_kernel<<<NB * 64, 256, 0, stream>>>(x, F);
    col_fft_kernel<<<NB * 8, 256, 0, stream>>>(F, sums);
    profile_kernel<<<NB, 256, 0, stream>>>(sums, w, bias, out);
}

// Round 2
// 134.516 us; speedup vs baseline: 1.1130x; 1.1130x over previous
//
#include <hip/hip_runtime.h>
#include <math.h>

#define NB 128        // batch
#define N 256         // FFT size / image dim
#define NBINS 181
#define THRESH 90
#define RS 136        // row stride (float2) of intermediate F, 64B-aligned rows
#define SR 17         // padded LDS row stride (floats) in col pass

__device__ __forceinline__ int bitrev8(int i) { return (int)(__brev((unsigned)i) >> 24); }

// ---------------- Row pass: gray + packed-pair 256-pt FFT, store k=0..128 ----------------
// grid: (32, NB), 256 threads. Each wave does one ROW PAIR (z = row0 + i*row1).
__global__ __launch_bounds__(256) void row_fft_kernel(const float* __restrict__ x,
                                                      float2* __restrict__ F) {
    __shared__ float s_re[4][N];
    __shared__ float s_im[4][N];
    __shared__ float tw_re[N/2];
    __shared__ float tw_im[N/2];

    const int t = threadIdx.x;
    const int w = t >> 6;
    const int lane = t & 63;
    const int b  = blockIdx.y;
    const int jp = blockIdx.x * 4 + w;      // pair index 0..127
    const int r0 = 2 * jp;

    if (t < N/2) {
        float s, c;
        sincosf(-6.283185307179586f * (float)t / (float)N, &s, &c);
        tw_re[t] = c; tw_im[t] = s;
    }

    const float* x0 = x + (size_t)b * 3 * (N*N) + (size_t)r0 * N;
    const float* x1 = x0 + N;
    #pragma unroll
    for (int k = 0; k < 4; ++k) {
        int i = lane + 64*k;
        float g0 = 0.2989f*x0[i] + 0.587f*x0[i + N*N] + 0.114f*x0[i + 2*N*N];
        float g1 = 0.2989f*x1[i] + 0.587f*x1[i + N*N] + 0.114f*x1[i + 2*N*N];
        int ri = bitrev8(i);
        s_re[w][ri] = g0;
        s_im[w][ri] = g1;
    }
    __syncthreads();

    for (int s = 1; s <= 8; ++s) {
        const int half = 1 << (s-1);
        const int tstr = N >> s;
        #pragma unroll
        for (int k = 0; k < 2; ++k) {
            int bf  = lane + 64*k;          // 0..127
            int grp = bf >> (s-1);
            int j   = bf & (half-1);
            int i1  = grp*(half<<1) + j;
            int i2  = i1 + half;
            float wr = tw_re[j*tstr], wi = tw_im[j*tstr];
            float br = s_re[w][i2], bi = s_im[w][i2];
            float tr = br*wr - bi*wi;
            float ti = br*wi + bi*wr;
            float ar = s_re[w][i1], ai = s_im[w][i1];
            s_re[w][i1] = ar + tr; s_im[w][i1] = ai + ti;
            s_re[w][i2] = ar - tr; s_im[w][i2] = ai - ti;
        }
        __syncthreads();
    }

    // Unpack packed real FFTs for k = 0..128 and store both rows.
    float2* o0 = F + ((size_t)b * N + r0) * RS;
    float2* o1 = o0 + RS;
    #pragma unroll
    for (int kk = 0; kk < 3; ++kk) {
        int k = lane + 64*kk;               // 0..63, 64..127, 128(lane0 only)
        if (kk == 2 && lane != 0) break;
        int m = (N - k) & (N-1);
        float a  = s_re[w][k], bb = s_im[w][k];
        float c  = s_re[w][m], d  = s_im[w][m];
        o0[k] = make_float2(0.5f*(a + c), 0.5f*(bb - d));
        o1[k] = make_float2(0.5f*(bb + d), 0.5f*(c - a));
    }
}

// ------------- Col pass: 256-pt FFT on cols 0..128 + log|F| + mirrored radial binning -------------
// grid: (9, NB), 256 threads. 16 columns per block.
__global__ __launch_bounds__(256) void col_fft_kernel(const float2* __restrict__ F,
                                                      float* __restrict__ sums) {
    __shared__ float s_re[N*SR];
    __shared__ float s_im[N*SR];
    __shared__ float tw_re[N/2];
    __shared__ float tw_im[N/2];
    __shared__ float bins[192];

    const int t = threadIdx.x;
    const int c = t & 15;
    const int q = t >> 4;                   // 0..15
    const int b  = blockIdx.y;
    const int cg = blockIdx.x;              // 0..8
    const int cglob = cg*16 + c;
    const bool valid = (cglob <= 128);

    if (t < N/2) {
        float s, co;
        sincosf(-6.283185307179586f * (float)t / (float)N, &s, &co);
        tw_re[t] = co; tw_im[t] = s;
    }
    if (t < 192) bins[t] = 0.0f;

    const float2* base = F + (size_t)b * N * RS;
    #pragma unroll 4
    for (int i = 0; i < 16; ++i) {
        int r = i*16 + q;
        float2 v = valid ? base[(size_t)r * RS + cglob] : make_float2(0.f, 0.f);
        int rr = bitrev8(r);
        s_re[rr*SR + c] = v.x;
        s_im[rr*SR + c] = v.y;
    }
    __syncthreads();

    for (int s = 1; s <= 8; ++s) {
        const int half = 1 << (s-1);
        const int tstr = N >> s;
        #pragma unroll 4
        for (int k = 0; k < 8; ++k) {
            int bf  = q*8 + k;              // 0..127
            int grp = bf >> (s-1);
            int j   = bf & (half-1);
            int i1  = grp*(half<<1) + j;
            int i2  = i1 + half;
            int a1  = i1*SR + c;
            int a2  = i2*SR + c;
            float wr = tw_re[j*tstr], wi = tw_im[j*tstr];
            float br = s_re[a2], bi = s_im[a2];
            float tr = br*wr - bi*wi;
            float ti = br*wi + bi*wr;
            float ar = s_re[a1], ai = s_im[a1];
            s_re[a1] = ar + tr; s_im[a1] = ai + ti;
            s_re[a2] = ar - tr; s_im[a2] = ai - ti;
        }
        __syncthreads();
    }

    // log-magnitude + fftshift + radial binning (self + mirror for cols 1..127)
    if (valid) {
        const float dx  = (float)((cglob + 128) & 255) - 127.5f;
        const float dxm = (float)((384 - cglob) & 255) - 127.5f;
        const bool mirror = (cglob >= 1) && (cglob <= 127);
        #pragma unroll 4
        for (int i = 0; i < 16; ++i) {
            int u = i*16 + q;
            float re = s_re[u*SR + c], im = s_im[u*SR + c];
            float mag = logf(sqrtf(re*re + im*im) + 1e-8f);
            float dy = (float)((u + 128) & 255) - 127.5f;
            int bin = (int)sqrtf(dx*dx + dy*dy);
            atomicAdd(&bins[bin], mag);
            if (mirror) {
                int u2 = (N - u) & 255;
                float dy2 = (float)((u2 + 128) & 255) - 127.5f;
                int bin2 = (int)sqrtf(dxm*dxm + dy2*dy2);
                atomicAdd(&bins[bin2], mag);
            }
        }
    }
    __syncthreads();
    if (t < NBINS) atomicAdd(&sums[b*NBINS + t], bins[t]);
}

// ------------- Profile: counts, mean, min/max-normalize, dot with w -------------
// grid: NB blocks, 256 threads.
__global__ __launch_bounds__(256) void profile_kernel(const float* __restrict__ sums,
                                                      const float* __restrict__ w,
                                                      const float* __restrict__ bias,
                                                      float* __restrict__ out) {
    __shared__ int   cnt[192];
    __shared__ float prof[192];
    __shared__ float wred[4][3];

    const int t = threadIdx.x;
    const int b = blockIdx.x;
    if (t < 192) cnt[t] = 0;
    __syncthreads();

    {
        float dy = (float)t - 127.5f;
        for (int xx = 0; xx < 256; ++xx) {
            float dxx = (float)xx - 127.5f;
            int bin = (int)sqrtf(dxx*dxx + dy*dy);
            atomicAdd(&cnt[bin], 1);
        }
    }
    __syncthreads();
    if (t < NBINS) prof[t] = sums[b*NBINS + t] / (float)cnt[t];
    __syncthreads();

    float v = (t < NBINS) ? prof[t] : prof[0];
    float mn = v, mx = v;
    #pragma unroll
    for (int m = 32; m >= 1; m >>= 1) {
        mn = fminf(mn, __shfl_xor(mn, m));
        mx = fmaxf(mx, __shfl_xor(mx, m));
    }
    if ((t & 63) == 0) { wred[t>>6][0] = mn; wred[t>>6][1] = mx; }
    __syncthreads();
    if (t == 0) {
        float a = wred[0][0], z = wred[0][1];
        for (int i = 1; i < 4; ++i) { a = fminf(a, wred[i][0]); z = fmaxf(z, wred[i][1]); }
        wred[0][0] = a; wred[0][1] = z;
    }
    __syncthreads();
    const float mnv = wred[0][0], mxv = wred[0][1];

    float part = 0.0f;
    if (t < THRESH) {
        float f = (prof[(NBINS - THRESH) + t] - mnv) / (mxv - mnv);
        if (f != f) f = 0.0f;      // NaN -> 0 (matches jnp.where(isnan))
        part = f * w[t];
    }
    #pragma unroll
    for (int m = 32; m >= 1; m >>= 1) part += __shfl_xor(part, m);
    if ((t & 63) == 0) wred[t>>6][2] = part;
    __syncthreads();
    if (t == 0) out[b] = wred[0][2] + wred[1][2] + wred[2][2] + wred[3][2] + bias[0];
}

extern "C" void kernel_launch(void* const* d_in, const int* in_sizes, int n_in,
                              void* d_out, int out_size, void* d_ws, size_t ws_size,
                              hipStream_t stream) {
    const float* x    = (const float*)d_in[0];  // (128,3,256,256)
    const float* w    = (const float*)d_in[1];  // (1,90)
    const float* bias = (const float*)d_in[2];  // (1,)
    float* out = (float*)d_out;                 // (128,1)

    float2* F   = (float2*)d_ws;                // 128*256*136 float2 = 35.65 MB
    float* sums = (float*)((char*)d_ws + (size_t)NB * N * RS * sizeof(float2));

    hipMemsetAsync(sums, 0, (size_t)NB * NBINS * sizeof(float), stream);
    row_fft_kernel<<<dim3(32, NB), 256, 0, stream>>>(x, F);
    col_fft_kernel<<<dim3(9, NB), 256, 0, stream>>>(F, sums);
    profile_kernel<<<NB, 256, 0, stream>>>(sums, w, bias, out);
}

// Round 3
// 118.561 us; speedup vs baseline: 1.2628x; 1.1346x over previous
//
#include <hip/hip_runtime.h>
#include <math.h>

#define NB 128        // batch
#define N 256         // FFT size / image dim
#define NBINS 181
#define THRESH 90
#define RS 136        // row stride (float2) of intermediate F

__device__ __forceinline__ int br4(int i) {
    return ((i&1)<<3) | ((i&2)<<1) | ((i&4)>>1) | ((i&8)>>3);
}

// W16^e = exp(-2*pi*i*e/16), e = 0..7  (folded at compile time after unroll)
__device__ const float TW16R[8] = { 1.f,  0.92387953f,  0.70710678f,  0.38268343f,
                                    0.f, -0.38268343f, -0.70710678f, -0.92387953f };
__device__ const float TW16I[8] = { 0.f, -0.38268343f, -0.70710678f, -0.92387953f,
                                   -1.f, -0.92387953f, -0.70710678f, -0.38268343f };

// W256^l = exp(-2*pi*i*l/256), l = 0..15
__device__ const float W256R[16] = {
    1.00000000f, 0.99969882f, 0.99879546f, 0.99729046f, 0.99518473f, 0.99247953f,
    0.98917651f, 0.98527764f, 0.98078528f, 0.97570213f, 0.97003125f, 0.96377607f,
    0.95694034f, 0.94952818f, 0.94154407f, 0.93299280f };
__device__ const float W256I[16] = {
    -0.00000000f, -0.02454123f, -0.04906767f, -0.07356456f, -0.09801714f, -0.12241068f,
    -0.14673047f, -0.17096189f, -0.19509032f, -0.21910124f, -0.24298018f, -0.26671276f,
    -0.29028468f, -0.31368174f, -0.33688985f, -0.35989504f };

// 16-pt DIT FFT, input in BIT-REVERSED order, output natural order. All in registers.
__device__ __forceinline__ void fft16(float2 v[16]) {
    #pragma unroll
    for (int s = 0; s < 4; ++s) {
        const int half = 1 << s;
        #pragma unroll
        for (int gg = 0; gg < 16; gg += 2*half) {
            #pragma unroll
            for (int j = 0; j < half; ++j) {
                const float wr = TW16R[j << (3 - s)];
                const float wi = TW16I[j << (3 - s)];
                float2 a = v[gg + j], b = v[gg + j + half];
                float tr = b.x*wr - b.y*wi;
                float ti = b.x*wi + b.y*wr;
                v[gg + j]        = make_float2(a.x + tr, a.y + ti);
                v[gg + j + half] = make_float2(a.x - tr, a.y - ti);
            }
        }
    }
}

// A[k1] *= W256^(l*k1), k1 = 0..15 (iterated powers, register-only)
__device__ __forceinline__ void twiddle256(float2 v[16], int l) {
    const float c = W256R[l], s = W256I[l];
    float wr = c, wi = s;
    #pragma unroll
    for (int k = 1; k < 16; ++k) {
        float xr = v[k].x, xi = v[k].y;
        v[k] = make_float2(xr*wr - xi*wi, xr*wi + xi*wr);
        float nr = wr*c - wi*s;
        float ni = wr*s + wi*c;
        wr = nr; wi = ni;
    }
}

// ---------------- Row pass: gray + packed-pair register FFT, store k=0..128 ----------------
// grid (8, NB), 256 threads. Block = 16 row pairs; 16 threads per FFT.
__global__ __launch_bounds__(256, 4) void row_fft_kernel(const float* __restrict__ x,
                                                         float2* __restrict__ F) {
    __shared__ float2 zbuf[16][256];   // 32 KB

    const int t = threadIdx.x;
    const int b = blockIdx.y;
    const int pbase = blockIdx.x * 16;

    // ---- staging: grayscale for 16 row pairs, float4-vectorized ----
    const int cidx = t & 63;           // float4 chunk in row
    const int sub  = t >> 6;           // wave id 0..3
    const float* xb = x + (size_t)b * 3 * N * N;
    #pragma unroll
    for (int i = 0; i < 4; ++i) {
        int p  = i*4 + sub;
        int r0 = (pbase + p) * 2;
        const float* p0 = xb + (size_t)r0 * N + cidx*4;
        float4 a0 = *(const float4*)(p0);
        float4 a1 = *(const float4*)(p0 + N*N);
        float4 a2 = *(const float4*)(p0 + 2*N*N);
        float4 b0 = *(const float4*)(p0 + N);
        float4 b1 = *(const float4*)(p0 + N*N + N);
        float4 b2 = *(const float4*)(p0 + 2*N*N + N);
        #pragma unroll
        for (int j = 0; j < 4; ++j) {
            float g0 = 0.2989f*((&a0.x)[j]) + 0.587f*((&a1.x)[j]) + 0.114f*((&a2.x)[j]);
            float g1 = 0.2989f*((&b0.x)[j]) + 0.587f*((&b1.x)[j]) + 0.114f*((&b2.x)[j]);
            zbuf[p][cidx*4 + j] = make_float2(g0, g1);
        }
    }
    __syncthreads();

    // ---- 256-pt FFT = 16x16 register decomposition ----
    const int g = t >> 4, l = t & 15;  // FFT group (= pair), thread-in-FFT (= n2)
    float2 v[16];
    #pragma unroll
    for (int i = 0; i < 16; ++i) v[i] = zbuf[g][16*br4(i) + l];
    fft16(v);
    twiddle256(v, l);
    // transpose within group (reuse zbuf[g]; same wave -> no barrier; rotate swizzle)
    #pragma unroll
    for (int k = 0; k < 16; ++k) zbuf[g][k*16 + ((l + k) & 15)] = v[k];
    #pragma unroll
    for (int i = 0; i < 16; ++i) v[i] = zbuf[g][l*16 + ((br4(i) + l) & 15)];
    fft16(v);                           // thread l holds Z[l + 16*k2]

    // ---- Hermitian unpack of packed pair (shuffle, no LDS) + store k=0..128 ----
    const int lane = t & 63;
    const int src  = (lane & 48) | ((16 - l) & 15);
    float2* o0 = F + ((size_t)b * N + (size_t)(pbase + g) * 2) * RS;
    float2* o1 = o0 + RS;
    #pragma unroll
    for (int k2 = 0; k2 < 8; ++k2) {
        float2 zm_s;
        zm_s.x = __shfl(v[15 - k2].x, src, 64);
        zm_s.y = __shfl(v[15 - k2].y, src, 64);
        float2 zm = (l == 0) ? v[(16 - k2) & 15] : zm_s;
        float2 z  = v[k2];
        int k = l + 16*k2;
        o0[k] = make_float2(0.5f*(z.x + zm.x), 0.5f*(z.y - zm.y));
        o1[k] = make_float2(0.5f*(z.y + zm.y), 0.5f*(zm.x - z.x));
    }
    if (l == 0) {
        float2 z = v[8];                // k = 128, self-mirrored
        o0[128] = make_float2(z.x, 0.f);
        o1[128] = make_float2(z.y, 0.f);
    }
}

// ------------- Col pass: register FFT per column + log|F| + mirrored radial binning -------------
// grid (9, NB), 256 threads. 16 columns per block, 16 threads per FFT.
__global__ __launch_bounds__(256, 4) void col_fft_kernel(const float2* __restrict__ F,
                                                         float* __restrict__ sums) {
    __shared__ float2 sbuf[256*17];    // 34.8 KB, stride-17 rows (also reused for transpose)
    __shared__ float bins[192];

    const int t = threadIdx.x;
    const int b  = blockIdx.y;
    const int cg = blockIdx.x;         // 0..8
    if (t < 192) bins[t] = 0.0f;

    // ---- staging: coalesced reads, padded LDS rows ----
    const int c = t & 15, q = t >> 4;
    const int colr = cg*16 + c;
    const bool vread = (colr <= 128);
    const float2* base = F + (size_t)b * N * RS;
    #pragma unroll
    for (int i = 0; i < 16; ++i) {
        int r = i*16 + q;
        float2 vv = vread ? base[(size_t)r * RS + colr] : make_float2(0.f, 0.f);
        sbuf[r*17 + c] = vv;
    }
    __syncthreads();

    const int g = t >> 4, l = t & 15;
    const int col = cg*16 + g;
    const bool valid = (col <= 128);
    float2 v[16];
    if (valid) {
        #pragma unroll
        for (int i = 0; i < 16; ++i) v[i] = sbuf[(16*br4(i) + l)*17 + g];
        fft16(v);
        twiddle256(v, l);
    }
    __syncthreads();                   // all sbuf reads done -> safe to overwrite
    if (valid) {
        // transpose in reused sbuf: per-group 16x17 region (stride 17 = conflict-free)
        #pragma unroll
        for (int k = 0; k < 16; ++k) sbuf[g*272 + k*17 + l] = v[k];
        #pragma unroll
        for (int i = 0; i < 16; ++i) v[i] = sbuf[g*272 + l*17 + br4(i)];
        fft16(v);                      // thread l holds X[u = l + 16*k2][col]

        // ---- log-magnitude + fftshift + radial binning (self + mirror) ----
        const float dx  = (float)((col + 128) & 255) - 127.5f;
        const float dxm = (float)((384 - col) & 255) - 127.5f;
        const bool mirror = (col >= 1) && (col <= 127);
        #pragma unroll
        for (int k2 = 0; k2 < 16; ++k2) {
            int u = l + 16*k2;
            float re = v[k2].x, im = v[k2].y;
            float mag = __logf(sqrtf(re*re + im*im) + 1e-8f);
            float dy = (float)((u + 128) & 255) - 127.5f;
            int bin = (int)sqrtf(dx*dx + dy*dy);
            atomicAdd(&bins[bin], mag);
            if (mirror) {
                int u2 = (N - u) & 255;
                float dy2 = (float)((u2 + 128) & 255) - 127.5f;
                int bin2 = (int)sqrtf(dxm*dxm + dy2*dy2);
                atomicAdd(&bins[bin2], mag);
            }
        }
    }
    __syncthreads();
    if (t < NBINS) atomicAdd(&sums[b*NBINS + t], bins[t]);
}

// ------------- Profile: counts, mean, min/max-normalize, dot with w -------------
__global__ __launch_bounds__(256) void profile_kernel(const float* __restrict__ sums,
                                                      const float* __restrict__ w,
                                                      const float* __restrict__ bias,
                                                      float* __restrict__ out) {
    __shared__ int   cnt[192];
    __shared__ float prof[192];
    __shared__ float wred[4][3];

    const int t = threadIdx.x;
    const int b = blockIdx.x;
    if (t < 192) cnt[t] = 0;
    __syncthreads();

    {
        float dy = (float)t - 127.5f;
        for (int xx = 0; xx < 256; ++xx) {
            float dxx = (float)xx - 127.5f;
            int bin = (int)sqrtf(dxx*dxx + dy*dy);
            atomicAdd(&cnt[bin], 1);
        }
    }
    __syncthreads();
    if (t < NBINS) prof[t] = sums[b*NBINS + t] / (float)cnt[t];
    __syncthreads();

    float vv = (t < NBINS) ? prof[t] : prof[0];
    float mn = vv, mx = vv;
    #pragma unroll
    for (int m = 32; m >= 1; m >>= 1) {
        mn = fminf(mn, __shfl_xor(mn, m));
        mx = fmaxf(mx, __shfl_xor(mx, m));
    }
    if ((t & 63) == 0) { wred[t>>6][0] = mn; wred[t>>6][1] = mx; }
    __syncthreads();
    if (t == 0) {
        float a = wred[0][0], z = wred[0][1];
        for (int i = 1; i < 4; ++i) { a = fminf(a, wred[i][0]); z = fmaxf(z, wred[i][1]); }
        wred[0][0] = a; wred[0][1] = z;
    }
    __syncthreads();
    const float mnv = wred[0][0], mxv = wred[0][1];

    float part = 0.0f;
    if (t < THRESH) {
        float f = (prof[(NBINS - THRESH) + t] - mnv) / (mxv - mnv);
        if (f != f) f = 0.0f;          // NaN -> 0
        part = f * w[t];
    }
    #pragma unroll
    for (int m = 32; m >= 1; m >>= 1) part += __shfl_xor(part, m);
    if ((t & 63) == 0) wred[t>>6][2] = part;
    __syncthreads();
    if (t == 0) out[b] = wred[0][2] + wred[1][2] + wred[2][2] + wred[3][2] + bias[0];
}

extern "C" void kernel_launch(void* const* d_in, const int* in_sizes, int n_in,
                              void* d_out, int out_size, void* d_ws, size_t ws_size,
                              hipStream_t stream) {
    const float* x    = (const float*)d_in[0];  // (128,3,256,256)
    const float* w    = (const float*)d_in[1];  // (1,90)
    const float* bias = (const float*)d_in[2];  // (1,)
    float* out = (float*)d_out;                 // (128,1)

    float2* F   = (float2*)d_ws;                // 128*256*136 float2 = 35.65 MB
    float* sums = (float*)((char*)d_ws + (size_t)NB * N * RS * sizeof(float2));

    hipMemsetAsync(sums, 0, (size_t)NB * NBINS * sizeof(float), stream);
    row_fft_kernel<<<dim3(8, NB), 256, 0, stream>>>(x, F);
    col_fft_kernel<<<dim3(9, NB), 256, 0, stream>>>(F, sums);
    profile_kernel<<<NB, 256, 0, stream>>>(sums, w, bias, out);
}